// Round 8
// baseline (93.595 us; speedup 1.0000x reference)
//
#include <hip/hip_runtime.h>
#include <hip/hip_bf16.h>
#include <math.h>

#define Bb 8
#define Nn 400
#define GN 2
#define INF 66        // INPUT_DIM + HIDDEN
#define IDIM 330      // logical K per d
#define KPW 384       // K padded so each d = 12 x 32 = 6 x 64
#define HID 64
#define EMB 16
#define NKP 416       // node-dim padded to 32
#define XTR 80        // XT rows (66 cols padded to 80)
constexpr int M = Bb * Nn;   // 3200 nodes

typedef __attribute__((ext_vector_type(8))) short short8;   // 8 x bf16 frag
typedef __attribute__((ext_vector_type(4))) float f32x4;

__device__ __forceinline__ ushort f2bf(float f) {
    union { float f; unsigned u; } v; v.f = f;
    unsigned u = v.u;
    unsigned r = (u + 0x7FFFu + ((u >> 16) & 1u)) >> 16;
    return (ushort)r;
}

// ================= prep: gconv(vec4) | wT(gates) | wT(cand) | concat =================
// grid 1-D: [0,2600) gconv, [2600,2984) wTg, [2984,3176) wTc, [3176,3232) concat
#define GBLKS4 2600
__global__ void k_prep(const float* __restrict__ G, const float* __restrict__ Wg,
                       const float* __restrict__ Wc, const float* __restrict__ x,
                       const float* __restrict__ state,
                       ushort* __restrict__ Gbf, ushort* __restrict__ WgT,
                       ushort* __restrict__ WcT, ushort* __restrict__ Hbf,
                       ushort* __restrict__ Hbf2, ushort* __restrict__ XTin) {
    __shared__ float Tw[32][65];
    __shared__ ushort Tc[64][XTR + 1];
    int bid = blockIdx.x;
    if (bid < GBLKS4) {
        // graphs -> bf16, 4 elems/thread, node-dim padded 400->416
        size_t tid4 = ((size_t)bid * 256 + threadIdx.x) * 4;
        int k = (int)(tid4 % NKP);
        size_t row = tid4 / NKP;
        ushort4 o;
        if (k < Nn) {
            float4 gv = *(const float4*)(G + row * Nn + k);
            o.x = f2bf(gv.x); o.y = f2bf(gv.y); o.z = f2bf(gv.z); o.w = f2bf(gv.w);
        } else {
            o.x = o.y = o.z = o.w = 0;
        }
        *(ushort4*)(Gbf + tid4) = o;
        return;
    }
    bid -= GBLKS4;
    if (bid < 384 + 192) {
        // W[d,i,o] -> WT[c=d*O+o][k], k padded to 384 (12 k-blocks of 32)
        const float* W; ushort* WT; int O;
        if (bid < 384) { W = Wg; WT = WgT; O = 128; }
        else           { bid -= 384; W = Wc; WT = WcT; O = 64; }
        const int k0 = (bid % 12) * 32;
        const int c0 = (bid / 12) * 64;
        const int d = c0 / O, o0 = c0 % O;
        for (int e = threadIdx.x; e < 2048; e += 256) {
            int kk = e >> 6, oo = e & 63;
            int k = k0 + kk;
            Tw[kk][oo] = (k < IDIM) ? W[((size_t)d * IDIM + k) * O + o0 + oo] : 0.f;
        }
        __syncthreads();
        for (int e = threadIdx.x; e < 2048; e += 256) {
            int cc = e >> 5, kk = e & 31;
            WT[(size_t)(c0 + cc) * KPW + k0 + kk] = f2bf(Tw[kk][cc]);
        }
        return;
    }
    bid -= 576;
    // concat x,state -> Hbf cols 0..65 (Hbf2 cols 0..1), zero pad 330..383 both, XTin
    const int b = bid / 7;
    const int k0 = (bid % 7) * 64;
    for (int e = threadIdx.x; e < 64 * XTR; e += 256) {
        int kk = e / XTR, c = e % XTR;
        int k = k0 + kk;
        ushort bf = 0;
        if (k < Nn && c < INF) {
            float v = (c < 2) ? x[((size_t)b * Nn + k) * 2 + c]
                              : state[((size_t)b * Nn + k) * HID + c - 2];
            bf = f2bf(v);
            Hbf[((size_t)b * Nn + k) * KPW + c] = bf;
            if (c < 2) Hbf2[((size_t)b * Nn + k) * KPW + c] = bf;
        }
        Tc[kk][c] = bf;
    }
    for (int e = threadIdx.x; e < 64 * 54; e += 256) {
        int kk = e / 54, c = 330 + e % 54;
        int k = k0 + kk;
        if (k < Nn) {
            Hbf[((size_t)b * Nn + k) * KPW + c] = 0;
            Hbf2[((size_t)b * Nn + k) * KPW + c] = 0;
        }
    }
    __syncthreads();
    for (int e = threadIdx.x; e < XTR * 64; e += 256) {
        int c = e / 64, kk = e % 64;
        int k = k0 + kk;
        if (k < NKP) XTin[((size_t)b * XTR + c) * NKP + k] = Tc[kk][c];
    }
}

// ================= graph hop via MFMA, LDS-free, 1-wave blocks (round-5 proven) =================
// grid (25, B, GN), block 64. Wave handles 16 rows x 80 cols, K=416 unrolled.
__global__ __launch_bounds__(64) void k_hop(const ushort* __restrict__ Gbf,
                      const ushort* __restrict__ XT,
                      ushort* __restrict__ Hb, ushort* __restrict__ XTnext,
                      int out_base, int xt_per_g) {
    const int b = blockIdx.y, g = blockIdx.z;
    const int row0 = blockIdx.x * 16;
    const int lane = threadIdx.x;
    const int lr = lane & 15, kq = lane >> 4;

    const ushort* Gb = Gbf + (size_t)(g * Bb + b) * Nn * NKP;
    const ushort* Xb = XT + (size_t)((xt_per_g ? g * Bb : 0) + b) * XTR * NKP;
    const ushort* Grow = Gb + (size_t)(row0 + lr) * NKP;   // row0+lr <= 399

    f32x4 acc[5] = {};
#pragma unroll
    for (int ks = 0; ks < 13; ++ks) {
        short8 af = *(const short8*)(Grow + ks * 32 + kq * 8);
#pragma unroll
        for (int n = 0; n < 5; ++n) {
            short8 bv = *(const short8*)(Xb + (size_t)(n * 16 + lr) * NKP + ks * 32 + kq * 8);
            acc[n] = __builtin_amdgcn_mfma_f32_16x16x32_bf16(af, bv, acc[n], 0, 0, 0);
        }
    }

    const int rbase = row0 + kq * 4;   // <= 396, rows exact
    ushort* Hout = Hb + (size_t)b * Nn * KPW + out_base + g * 132;
#pragma unroll
    for (int n = 0; n < 5; ++n) {
        int col = n * 16 + lr;
        if (col < INF) {
#pragma unroll
            for (int r = 0; r < 4; ++r)
                Hout[(size_t)(rbase + r) * KPW + col] = f2bf(acc[n][r]);
        }
    }
    if (XTnext) {
        ushort* Xn = XTnext + (size_t)(g * Bb + b) * XTR * NKP;
#pragma unroll
        for (int n = 0; n < 5; ++n) {
            int col = n * 16 + lr;
            ushort4 w;
#pragma unroll
            for (int r = 0; r < 4; ++r)
                w[r] = (col < INF) ? f2bf(acc[n][r]) : (ushort)0;
            *(ushort4*)(Xn + (size_t)col * NKP + rbase) = w;
        }
    }
}

// ================= mono meta GEMM: all 16 d in-block, fused epilogue =================
// out[m,o] = act( sum_d e[m,d]*(sum_k H[m,k]*W[d,k,o] + bg[d,o]) )
// BM=32, BN=64, grid (O/64, 100), block 256 (4 waves 2x2; wave = 16 rows x 32 cols).
// A (32x384) staged ONCE in LDS; B double-buffered + reg-prefetched, 1 barrier/step;
// e-fold + bias-fold in registers at each d boundary (every 6 steps of K=64).
// MODE 0 (gates, O=128): bo=0 -> z into zb; bo=64 -> r: writes r*state to Hdst+XTin.
// MODE 1 (final, O=64): hc=tanh, GRU blend -> out.
template <int O, int MODE>
__global__ __launch_bounds__(256) void k_meta_mono(
    const ushort* __restrict__ Hsrc, const ushort* __restrict__ WT,
    const float* __restrict__ emb, const float* __restrict__ bias,
    const float* __restrict__ state, float* __restrict__ zb,
    float* __restrict__ out, ushort* __restrict__ Hdst, ushort* __restrict__ XTin) {
    __shared__ ushort As[32][392];          // 24.5 KB, full K for the 32-row tile
    __shared__ ushort Bs[2][2][64][40];     // 20.5 KB: dbuf x sub x col x k
    __shared__ float es[32][EMB];           // 2 KB
    __shared__ float bgs[EMB][64];          // 4 KB
    const int bo = blockIdx.x * 64, bm = blockIdx.y * 32;
    const int t = threadIdx.x;
    const int wid = t >> 6, lane = t & 63;
    const int wm = wid >> 1, wn = wid & 1;
    const int lr = lane & 15, kq = lane >> 4;

    {   // stage e-tile [32 rows][16 d]
        int i = t * 2;
        float2 ev = *(const float2*)(emb + (size_t)bm * EMB + i);
        es[i >> 4][i & 15] = ev.x;
        es[i >> 4][(i & 15) + 1] = ev.y;
    }
#pragma unroll
    for (int p = 0; p < 4; ++p) {   // stage bias tile [16][64]
        int i = t + p * 256;
        bgs[i >> 6][i & 63] = bias[(size_t)(i >> 6) * O + bo + (i & 63)];
    }
#pragma unroll
    for (int p = 0; p < 6; ++p) {   // stage A once: 1536 short8 slots
        int slot = t + p * 256;
        int row = slot / 48, kc = (slot % 48) * 8;
        *(short8*)&As[row][kc] = *(const short8*)(Hsrc + (size_t)(bm + row) * KPW + kc);
    }

    // B staging slots: 512 short8 per step (2 subs x 64 cols x 4 chunks), 2/thread
    int bsub[2], bcol[2], bkc[2];
#pragma unroll
    for (int q = 0; q < 2; ++q) {
        int c = t + q * 256;
        bsub[q] = c >> 8; bcol[q] = (c >> 2) & 63; bkc[q] = (c & 3) * 8;
    }
    short8 rB[2];
#pragma unroll
    for (int q = 0; q < 2; ++q)
        rB[q] = *(const short8*)(WT + (size_t)(bo + bcol[q]) * KPW + bsub[q] * 32 + bkc[q]);

    f32x4 seg[2] = {}, val[2] = {};

    for (int d = 0; d < 16; ++d) {
#pragma unroll
        for (int s = 0; s < 6; ++s) {
            const int step = d * 6 + s;
            const int buf = step & 1;
#pragma unroll
            for (int q = 0; q < 2; ++q)
                *(short8*)&Bs[buf][bsub[q]][bcol[q]][bkc[q]] = rB[q];
            if (step < 95) {
                const int nd = (s == 5) ? d + 1 : d;
                const int ns = (s == 5) ? 0 : s + 1;
#pragma unroll
                for (int q = 0; q < 2; ++q)
                    rB[q] = *(const short8*)(WT + (size_t)(nd * O + bo + bcol[q]) * KPW
                                             + ns * 64 + bsub[q] * 32 + bkc[q]);
            }
            __syncthreads();
            short8 a0 = *(const short8*)&As[wm * 16 + lr][s * 64 + kq * 8];
            short8 a1 = *(const short8*)&As[wm * 16 + lr][s * 64 + 32 + kq * 8];
#pragma unroll
            for (int n = 0; n < 2; ++n) {
                short8 b0 = *(const short8*)&Bs[buf][0][wn * 32 + n * 16 + lr][kq * 8];
                short8 b1 = *(const short8*)&Bs[buf][1][wn * 32 + n * 16 + lr][kq * 8];
                seg[n] = __builtin_amdgcn_mfma_f32_16x16x32_bf16(a0, b0, seg[n], 0, 0, 0);
                seg[n] = __builtin_amdgcn_mfma_f32_16x16x32_bf16(a1, b1, seg[n], 0, 0, 0);
            }
        }
        // d-boundary: fold e and bias into val, reset seg
#pragma unroll
        for (int r = 0; r < 4; ++r) {
            float e = es[wm * 16 + kq * 4 + r][d];
#pragma unroll
            for (int n = 0; n < 2; ++n) {
                val[n][r] += e * (seg[n][r] + bgs[d][wn * 32 + n * 16 + lr]);
                seg[n][r] = 0.f;
            }
        }
    }

    const int row0_ = bm + wm * 16 + kq * 4;
    if constexpr (MODE == 0) {
#pragma unroll
        for (int n = 0; n < 2; ++n) {
            const int o = bo + wn * 32 + n * 16 + lr;
            if (o < 64) {
#pragma unroll
                for (int r = 0; r < 4; ++r)
                    zb[(row0_ + r) * 64 + o] = 1.f / (1.f + expf(-val[n][r]));
            } else {
                const int oo = o - 64;
                ushort4 w;
#pragma unroll
                for (int r = 0; r < 4; ++r) {
                    float sg = 1.f / (1.f + expf(-val[n][r]));
                    ushort bfv = f2bf(sg * state[(size_t)(row0_ + r) * 64 + oo]);
                    Hdst[(size_t)(row0_ + r) * KPW + 2 + oo] = bfv;
                    w[r] = bfv;
                }
                int b = row0_ / Nn, kn = row0_ % Nn;   // 4-row group never straddles (400%4==0)
                *(ushort4*)(XTin + ((size_t)b * XTR + 2 + oo) * NKP + kn) = w;
            }
        }
    } else {
#pragma unroll
        for (int n = 0; n < 2; ++n) {
            const int o = wn * 32 + n * 16 + lr;
#pragma unroll
            for (int r = 0; r < 4; ++r) {
                const int row = row0_ + r;
                float hc = tanhf(val[n][r]);
                float z = zb[row * 64 + o];
                out[row * 64 + o] = z * state[row * 64 + o] + (1.f - z) * hc;
            }
        }
    }
}

extern "C" void kernel_launch(void* const* d_in, const int* in_sizes, int n_in,
                              void* d_out, int out_size, void* d_ws, size_t ws_size,
                              hipStream_t stream) {
    const float* x      = (const float*)d_in[0];
    const float* state  = (const float*)d_in[1];
    const float* graphs = (const float*)d_in[2];
    const float* emb    = (const float*)d_in[3];
    const float* Wg     = (const float*)d_in[4];
    const float* bg     = (const float*)d_in[5];
    const float* Wc     = (const float*)d_in[6];
    const float* bc     = (const float*)d_in[7];
    float* out = (float*)d_out;

    char* ws = (char*)d_ws;
    ushort* Hbf  = (ushort*)ws;  ws += (size_t)M * KPW * 2;                // 2.46 MB
    ushort* Hbf2 = (ushort*)ws;  ws += (size_t)M * KPW * 2;                // 2.46 MB
    ushort* Gbf  = (ushort*)ws;  ws += (size_t)GN * Bb * Nn * NKP * 2;     // 5.32 MB
    ushort* WgT  = (ushort*)ws;  ws += (size_t)2048 * KPW * 2;             // 1.57 MB
    ushort* WcT  = (ushort*)ws;  ws += (size_t)1024 * KPW * 2;             // 0.79 MB
    ushort* XTin = (ushort*)ws;  ws += (size_t)Bb * XTR * NKP * 2;         // 0.53 MB
    ushort* XTmid= (ushort*)ws;  ws += (size_t)GN * Bb * XTR * NKP * 2;    // 1.06 MB
    float*  zb   = (float*)ws;                                             // 0.82 MB

    dim3 hopgrid(25, Bb, GN);

    k_prep<<<3232, 256, 0, stream>>>(graphs, Wg, Wc, x, state, Gbf, WgT, WcT, Hbf, Hbf2, XTin);

    // ---- first meta_dgcn (gates): read Hbf -> z (zb), r*state (Hbf2 + XTin) ----
    k_hop<<<hopgrid, 64, 0, stream>>>(Gbf, XTin, Hbf, XTmid, 66, 0);
    k_hop<<<hopgrid, 64, 0, stream>>>(Gbf, XTmid, Hbf, nullptr, 132, 1);
    k_meta_mono<128, 0><<<dim3(2, 100), 256, 0, stream>>>(Hbf, WgT, emb, bg, state, zb,
                                                          nullptr, Hbf2, XTin);

    // ---- second meta_dgcn (candidate): read Hbf2 -> GRU blend -> out ----
    k_hop<<<hopgrid, 64, 0, stream>>>(Gbf, XTin, Hbf2, XTmid, 66, 0);
    k_hop<<<hopgrid, 64, 0, stream>>>(Gbf, XTmid, Hbf2, nullptr, 132, 1);
    k_meta_mono<64, 1><<<dim3(1, 100), 256, 0, stream>>>(Hbf2, WcT, emb, bc, state, zb,
                                                         out, nullptr, nullptr);
}

// Round 9
// 92.747 us; speedup vs baseline: 1.0091x; 1.0091x over previous
//
#include <hip/hip_runtime.h>
#include <hip/hip_bf16.h>
#include <math.h>

#define Bb 8
#define Nn 400
#define GN 2
#define INF 66        // INPUT_DIM + HIDDEN
#define IDIM 330      // logical K
#define KP 352        // K padded to 32
#define HID 64
#define EMB 16
#define NKP 416       // node-dim padded to 32
#define XTR 80        // XT rows (66 cols padded to 80)
constexpr int M = Bb * Nn;   // 3200 nodes

typedef __attribute__((ext_vector_type(8))) short short8;   // 8 x bf16 frag
typedef __attribute__((ext_vector_type(4))) float f32x4;

__device__ __forceinline__ ushort f2bf(float f) {
    union { float f; unsigned u; } v; v.f = f;
    unsigned u = v.u;
    unsigned r = (u + 0x7FFFu + ((u >> 16) & 1u)) >> 16;
    return (ushort)r;
}

// ================= prep: gconv(vec4) | wT(gates) | wT(cand) | concat =================
// grid 1-D: [0,2600) gconv, [2600,3128) wT, [3128,3184) concat
#define GBLKS4 2600
__global__ void k_prep(const float* __restrict__ G, const float* __restrict__ Wg,
                       const float* __restrict__ Wc, const float* __restrict__ x,
                       const float* __restrict__ state,
                       ushort* __restrict__ Gbf, ushort* __restrict__ WgT,
                       ushort* __restrict__ WcT, ushort* __restrict__ Hbf,
                       ushort* __restrict__ XTin) {
    __shared__ float Tw[32][65];
    __shared__ ushort Tc[64][XTR + 1];
    int bid = blockIdx.x;
    if (bid < GBLKS4) {
        // graphs -> bf16, 4 elems/thread, node-dim padded 400->416
        size_t tid4 = ((size_t)bid * 256 + threadIdx.x) * 4;
        int k = (int)(tid4 % NKP);
        size_t row = tid4 / NKP;
        ushort4 o;
        if (k < Nn) {
            float4 gv = *(const float4*)(G + row * Nn + k);
            o.x = f2bf(gv.x); o.y = f2bf(gv.y); o.z = f2bf(gv.z); o.w = f2bf(gv.w);
        } else {
            o.x = o.y = o.z = o.w = 0;
        }
        *(ushort4*)(Gbf + tid4) = o;
        return;
    }
    bid -= GBLKS4;
    if (bid < 352 + 176) {
        // W[d,i,o] -> WT[c=d*O+o][k], k padded to 352
        const float* W; ushort* WT; int O;
        if (bid < 352) { W = Wg; WT = WgT; O = 128; }
        else           { bid -= 352; W = Wc; WT = WcT; O = 64; }
        const int k0 = (bid % 11) * 32;
        const int c0 = (bid / 11) * 64;
        const int d = c0 / O, o0 = c0 % O;
        for (int e = threadIdx.x; e < 2048; e += 256) {
            int kk = e >> 6, oo = e & 63;
            int k = k0 + kk;
            Tw[kk][oo] = (k < IDIM) ? W[((size_t)d * IDIM + k) * O + o0 + oo] : 0.f;
        }
        __syncthreads();
        for (int e = threadIdx.x; e < 2048; e += 256) {
            int cc = e >> 5, kk = e & 31;
            WT[(size_t)(c0 + cc) * KP + k0 + kk] = f2bf(Tw[kk][cc]);
        }
        return;
    }
    bid -= 528;
    // concat x,state -> Hbf cols 0..65 (+zero pad 330..351) AND XTin[b][c][k]
    const int b = bid / 7;
    const int k0 = (bid % 7) * 64;
    for (int e = threadIdx.x; e < 64 * XTR; e += 256) {
        int kk = e / XTR, c = e % XTR;
        int k = k0 + kk;
        ushort bf = 0;
        if (k < Nn && c < INF) {
            float v = (c < 2) ? x[((size_t)b * Nn + k) * 2 + c]
                              : state[((size_t)b * Nn + k) * HID + c - 2];
            bf = f2bf(v);
            Hbf[((size_t)b * Nn + k) * KP + c] = bf;
        }
        Tc[kk][c] = bf;
    }
    for (int e = threadIdx.x; e < 64 * 22; e += 256) {
        int kk = e / 22, c = 330 + e % 22;
        int k = k0 + kk;
        if (k < Nn) Hbf[((size_t)b * Nn + k) * KP + c] = 0;
    }
    __syncthreads();
    for (int e = threadIdx.x; e < XTR * 64; e += 256) {
        int c = e / 64, kk = e % 64;
        int k = k0 + kk;
        if (k < NKP) XTin[((size_t)b * XTR + c) * NKP + k] = Tc[kk][c];
    }
}

// ================= graph hop via MFMA, LDS-free, 1-wave blocks (round-5 proven) =================
// grid (25, B, GN), block 64. Wave handles 16 rows x 80 cols, K=416 unrolled.
__global__ __launch_bounds__(64) void k_hop(const ushort* __restrict__ Gbf,
                      const ushort* __restrict__ XT,
                      ushort* __restrict__ Hb, ushort* __restrict__ XTnext,
                      int out_base, int xt_per_g) {
    const int b = blockIdx.y, g = blockIdx.z;
    const int row0 = blockIdx.x * 16;
    const int lane = threadIdx.x;
    const int lr = lane & 15, kq = lane >> 4;

    const ushort* Gb = Gbf + (size_t)(g * Bb + b) * Nn * NKP;
    const ushort* Xb = XT + (size_t)((xt_per_g ? g * Bb : 0) + b) * XTR * NKP;
    const ushort* Grow = Gb + (size_t)(row0 + lr) * NKP;   // row0+lr <= 399

    f32x4 acc[5] = {};
#pragma unroll
    for (int ks = 0; ks < 13; ++ks) {
        short8 af = *(const short8*)(Grow + ks * 32 + kq * 8);
#pragma unroll
        for (int n = 0; n < 5; ++n) {
            short8 bv = *(const short8*)(Xb + (size_t)(n * 16 + lr) * NKP + ks * 32 + kq * 8);
            acc[n] = __builtin_amdgcn_mfma_f32_16x16x32_bf16(af, bv, acc[n], 0, 0, 0);
        }
    }

    const int rbase = row0 + kq * 4;   // <= 396, rows exact
    ushort* Hout = Hb + (size_t)b * Nn * KP + out_base + g * 132;
#pragma unroll
    for (int n = 0; n < 5; ++n) {
        int col = n * 16 + lr;
        if (col < INF) {
#pragma unroll
            for (int r = 0; r < 4; ++r)
                Hout[(size_t)(rbase + r) * KP + col] = f2bf(acc[n][r]);
        }
    }
    if (XTnext) {
        ushort* Xn = XTnext + (size_t)(g * Bb + b) * XTR * NKP;
#pragma unroll
        for (int n = 0; n < 5; ++n) {
            int col = n * 16 + lr;
            ushort4 w;
#pragma unroll
            for (int r = 0; r < 4; ++r)
                w[r] = (col < INF) ? f2bf(acc[n][r]) : (ushort)0;
            *(ushort4*)(Xn + (size_t)col * NKP + rbase) = w;
        }
    }
}

// ================= fused meta GEMM, no-LDS: frags direct from global (L2-resident) =================
// grid (8, 50), block 256 (4 waves: wm=rows-half, wn=cols-half). Each block: 2 d's
// sharing A; 11 fully-unrolled K-steps, no barriers. Writes fp32 partials P[ds][m][o].
template <int O>
__global__ __launch_bounds__(256) void k_meta_ng(const ushort* __restrict__ Hbf,
        const ushort* __restrict__ WT, const float* __restrict__ emb,
        float* __restrict__ P) {
    constexpr int NB = O / 32;      // col frags per wave (128->4, 64->2)
    const int ds = blockIdx.x;
    const int bm = blockIdx.y * 64;
    const int t = threadIdx.x;
    const int wid = t >> 6, lane = t & 63;
    const int wm = wid >> 1, wn = wid & 1;
    const int lr = lane & 15, kq = lane >> 4;

    const ushort* Arow[2];
#pragma unroll
    for (int m = 0; m < 2; ++m)
        Arow[m] = Hbf + (size_t)(bm + wm * 32 + m * 16 + lr) * KP + kq * 8;
    const ushort* Brow[2][NB];
#pragma unroll
    for (int j = 0; j < 2; ++j)
#pragma unroll
        for (int n = 0; n < NB; ++n)
            Brow[j][n] = WT + (size_t)((ds * 2 + j) * O + wn * (O / 2) + n * 16 + lr) * KP + kq * 8;

    f32x4 seg[2][2][NB] = {};   // [d][m][n]
#pragma unroll
    for (int ks = 0; ks < 11; ++ks) {
        short8 a[2];
#pragma unroll
        for (int m = 0; m < 2; ++m) a[m] = *(const short8*)(Arow[m] + ks * 32);
#pragma unroll
        for (int j = 0; j < 2; ++j)
#pragma unroll
            for (int n = 0; n < NB; ++n) {
                short8 bv = *(const short8*)(Brow[j][n] + ks * 32);
#pragma unroll
                for (int m = 0; m < 2; ++m)
                    seg[j][m][n] = __builtin_amdgcn_mfma_f32_16x16x32_bf16(a[m], bv, seg[j][m][n], 0, 0, 0);
            }
    }

    float* Pd = P + (size_t)ds * M * O;
#pragma unroll
    for (int m = 0; m < 2; ++m) {
        const int rbase = bm + wm * 32 + m * 16 + kq * 4;
#pragma unroll
        for (int r = 0; r < 4; ++r) {
            const int row = rbase + r;
            float e0 = emb[(size_t)row * EMB + ds * 2];
            float e1 = emb[(size_t)row * EMB + ds * 2 + 1];
#pragma unroll
            for (int n = 0; n < NB; ++n) {
                const int col = wn * (O / 2) + n * 16 + lr;
                Pd[(size_t)row * O + col] = e0 * seg[0][m][n][r] + e1 * seg[1][m][n][r];
            }
        }
    }
}

// ================= z/r: sum partials + bias + sigmoid; write z, r*state =================
__global__ void k_zr(const float* __restrict__ P, const float* __restrict__ emb,
                     const float* __restrict__ bg, const float* __restrict__ state,
                     float* __restrict__ zbuf, ushort* __restrict__ Hbf,
                     ushort* __restrict__ XTin) {
    __shared__ float es[2][EMB];
    const int t = threadIdx.x;
    if (t < 2 * EMB) es[t >> 4][t & 15] = emb[((size_t)blockIdx.x * 2 + (t >> 4)) * EMB + (t & 15)];
    __syncthreads();
    const int node = blockIdx.x * 2 + (t >> 7);
    const int o = t & 127;
    float v = 0.f;
#pragma unroll
    for (int s = 0; s < 8; ++s) v += P[((size_t)s * M + node) * 128 + o];
    const float* e_ = es[t >> 7];
#pragma unroll
    for (int d = 0; d < EMB; ++d) v += e_[d] * bg[d * 128 + o];
    float sg = 1.f / (1.f + expf(-v));
    if (o < 64) {
        zbuf[node * 64 + o] = sg;
    } else {
        int oo = o - 64;
        ushort bf = f2bf(sg * state[node * 64 + oo]);
        Hbf[(size_t)node * KP + 2 + oo] = bf;
        int b = node / Nn, kn = node % Nn;
        XTin[((size_t)b * XTR + 2 + oo) * NKP + kn] = bf;
    }
}

// ================= final: sum partials + bias + tanh + GRU blend =================
__global__ void k_final(const float* __restrict__ P, const float* __restrict__ emb,
                        const float* __restrict__ bc, const float* __restrict__ zbuf,
                        const float* __restrict__ state, float* __restrict__ out) {
    __shared__ float es[4][EMB];
    const int t = threadIdx.x;
    if (t < 4 * EMB) es[t >> 4][t & 15] = emb[((size_t)blockIdx.x * 4 + (t >> 4)) * EMB + (t & 15)];
    __syncthreads();
    const int node = blockIdx.x * 4 + (t >> 6);
    const int o = t & 63;
    float v = 0.f;
#pragma unroll
    for (int s = 0; s < 8; ++s) v += P[((size_t)s * M + node) * 64 + o];
    const float* e_ = es[t >> 6];
#pragma unroll
    for (int d = 0; d < EMB; ++d) v += e_[d] * bc[d * 64 + o];
    float hc = tanhf(v);
    float z = zbuf[node * 64 + o];
    out[node * 64 + o] = z * state[node * 64 + o] + (1.f - z) * hc;
}

extern "C" void kernel_launch(void* const* d_in, const int* in_sizes, int n_in,
                              void* d_out, int out_size, void* d_ws, size_t ws_size,
                              hipStream_t stream) {
    const float* x      = (const float*)d_in[0];
    const float* state  = (const float*)d_in[1];
    const float* graphs = (const float*)d_in[2];
    const float* emb    = (const float*)d_in[3];
    const float* Wg     = (const float*)d_in[4];
    const float* bg     = (const float*)d_in[5];
    const float* Wc     = (const float*)d_in[6];
    const float* bc     = (const float*)d_in[7];
    float* out = (float*)d_out;

    char* ws = (char*)d_ws;
    ushort* Hbf  = (ushort*)ws;  ws += (size_t)M * KP * 2;                 // 2.25 MB
    ushort* Gbf  = (ushort*)ws;  ws += (size_t)GN * Bb * Nn * NKP * 2;     // 5.32 MB
    ushort* WgT  = (ushort*)ws;  ws += (size_t)2048 * KP * 2;              // 1.44 MB
    ushort* WcT  = (ushort*)ws;  ws += (size_t)1024 * KP * 2;              // 0.72 MB
    ushort* XTin = (ushort*)ws;  ws += (size_t)Bb * XTR * NKP * 2;         // 0.53 MB
    ushort* XTmid= (ushort*)ws;  ws += (size_t)GN * Bb * XTR * NKP * 2;    // 1.06 MB
    float*  PG   = (float*)ws;   ws += (size_t)8 * M * 128 * 4;            // 13.1 MB
    float*  PC   = (float*)ws;   ws += (size_t)8 * M * 64 * 4;             // 6.55 MB
    float*  zb   = (float*)ws;                                             // 0.82 MB

    dim3 hopgrid(25, Bb, GN);

    k_prep<<<3184, 256, 0, stream>>>(graphs, Wg, Wc, x, state, Gbf, WgT, WcT, Hbf, XTin);

    // ---- first meta_dgcn (gates) ----
    k_hop<<<hopgrid, 64, 0, stream>>>(Gbf, XTin, Hbf, XTmid, 66, 0);
    k_hop<<<hopgrid, 64, 0, stream>>>(Gbf, XTmid, Hbf, nullptr, 132, 1);
    k_meta_ng<128><<<dim3(8, 50), 256, 0, stream>>>(Hbf, WgT, emb, PG);
    k_zr<<<1600, 256, 0, stream>>>(PG, emb, bg, state, zb, Hbf, XTin);

    // ---- second meta_dgcn (candidate) ----
    k_hop<<<hopgrid, 64, 0, stream>>>(Gbf, XTin, Hbf, XTmid, 66, 0);
    k_hop<<<hopgrid, 64, 0, stream>>>(Gbf, XTmid, Hbf, nullptr, 132, 1);
    k_meta_ng<64><<<dim3(8, 50), 256, 0, stream>>>(Hbf, WcT, emb, PC);
    k_final<<<800, 256, 0, stream>>>(PC, emb, bc, zb, state, out);
}

// Round 10
// 73.729 us; speedup vs baseline: 1.2695x; 1.2579x over previous
//
#include <hip/hip_runtime.h>
#include <hip/hip_bf16.h>
#include <math.h>

#define Bb 8
#define Nn 400
#define GN 2
#define INF 66        // INPUT_DIM + HIDDEN
#define IDIM 330      // logical K
#define KP 352        // K padded to 32
#define HID 64
#define EMB 16
#define NKP 416       // node-dim padded to 32
#define XTR 80        // XT rows (66 cols padded to 80)
constexpr int M = Bb * Nn;   // 3200 nodes

typedef __attribute__((ext_vector_type(8))) short short8;   // 8 x bf16 frag
typedef __attribute__((ext_vector_type(4))) float f32x4;

__device__ __forceinline__ ushort f2bf(float f) {
    union { float f; unsigned u; } v; v.f = f;
    unsigned u = v.u;
    unsigned r = (u + 0x7FFFu + ((u >> 16) & 1u)) >> 16;
    return (ushort)r;
}

// ================= prep: gconv(vec4) | wT(gates) | wT(cand) | concat =================
// grid 1-D: [0,2600) gconv, [2600,3128) wT, [3128,3184) concat
#define GBLKS4 2600
__global__ void k_prep(const float* __restrict__ G, const float* __restrict__ Wg,
                       const float* __restrict__ Wc, const float* __restrict__ x,
                       const float* __restrict__ state,
                       ushort* __restrict__ Gbf, ushort* __restrict__ WgT,
                       ushort* __restrict__ WcT, ushort* __restrict__ Hbf,
                       ushort* __restrict__ XTin) {
    __shared__ float Tw[32][65];
    __shared__ ushort Tc[64][XTR + 1];
    int bid = blockIdx.x;
    if (bid < GBLKS4) {
        size_t tid4 = ((size_t)bid * 256 + threadIdx.x) * 4;
        int k = (int)(tid4 % NKP);
        size_t row = tid4 / NKP;
        ushort4 o;
        if (k < Nn) {
            float4 gv = *(const float4*)(G + row * Nn + k);
            o.x = f2bf(gv.x); o.y = f2bf(gv.y); o.z = f2bf(gv.z); o.w = f2bf(gv.w);
        } else {
            o.x = o.y = o.z = o.w = 0;
        }
        *(ushort4*)(Gbf + tid4) = o;
        return;
    }
    bid -= GBLKS4;
    if (bid < 352 + 176) {
        const float* W; ushort* WT; int O;
        if (bid < 352) { W = Wg; WT = WgT; O = 128; }
        else           { bid -= 352; W = Wc; WT = WcT; O = 64; }
        const int k0 = (bid % 11) * 32;
        const int c0 = (bid / 11) * 64;
        const int d = c0 / O, o0 = c0 % O;
        for (int e = threadIdx.x; e < 2048; e += 256) {
            int kk = e >> 6, oo = e & 63;
            int k = k0 + kk;
            Tw[kk][oo] = (k < IDIM) ? W[((size_t)d * IDIM + k) * O + o0 + oo] : 0.f;
        }
        __syncthreads();
        for (int e = threadIdx.x; e < 2048; e += 256) {
            int cc = e >> 5, kk = e & 31;
            WT[(size_t)(c0 + cc) * KP + k0 + kk] = f2bf(Tw[kk][cc]);
        }
        return;
    }
    bid -= 528;
    const int b = bid / 7;
    const int k0 = (bid % 7) * 64;
    for (int e = threadIdx.x; e < 64 * XTR; e += 256) {
        int kk = e / XTR, c = e % XTR;
        int k = k0 + kk;
        ushort bf = 0;
        if (k < Nn && c < INF) {
            float v = (c < 2) ? x[((size_t)b * Nn + k) * 2 + c]
                              : state[((size_t)b * Nn + k) * HID + c - 2];
            bf = f2bf(v);
            Hbf[((size_t)b * Nn + k) * KP + c] = bf;
        }
        Tc[kk][c] = bf;
    }
    for (int e = threadIdx.x; e < 64 * 22; e += 256) {
        int kk = e / 22, c = 330 + e % 22;
        int k = k0 + kk;
        if (k < Nn) Hbf[((size_t)b * Nn + k) * KP + c] = 0;
    }
    __syncthreads();
    for (int e = threadIdx.x; e < XTR * 64; e += 256) {
        int c = e / 64, kk = e % 64;
        int k = k0 + kk;
        if (k < NKP) XTin[((size_t)b * XTR + c) * NKP + k] = Tc[kk][c];
    }
}

// ================= graph hop via MFMA, LDS-free, 1-wave blocks (round-5 proven) =================
__global__ __launch_bounds__(64) void k_hop(const ushort* __restrict__ Gbf,
                      const ushort* __restrict__ XT,
                      ushort* __restrict__ Hb, ushort* __restrict__ XTnext,
                      int out_base, int xt_per_g) {
    const int b = blockIdx.y, g = blockIdx.z;
    const int row0 = blockIdx.x * 16;
    const int lane = threadIdx.x;
    const int lr = lane & 15, kq = lane >> 4;

    const ushort* Gb = Gbf + (size_t)(g * Bb + b) * Nn * NKP;
    const ushort* Xb = XT + (size_t)((xt_per_g ? g * Bb : 0) + b) * XTR * NKP;
    const ushort* Grow = Gb + (size_t)(row0 + lr) * NKP;

    f32x4 acc[5] = {};
#pragma unroll
    for (int ks = 0; ks < 13; ++ks) {
        short8 af = *(const short8*)(Grow + ks * 32 + kq * 8);
#pragma unroll
        for (int n = 0; n < 5; ++n) {
            short8 bv = *(const short8*)(Xb + (size_t)(n * 16 + lr) * NKP + ks * 32 + kq * 8);
            acc[n] = __builtin_amdgcn_mfma_f32_16x16x32_bf16(af, bv, acc[n], 0, 0, 0);
        }
    }

    const int rbase = row0 + kq * 4;
    ushort* Hout = Hb + (size_t)b * Nn * KP + out_base + g * 132;
#pragma unroll
    for (int n = 0; n < 5; ++n) {
        int col = n * 16 + lr;
        if (col < INF) {
#pragma unroll
            for (int r = 0; r < 4; ++r)
                Hout[(size_t)(rbase + r) * KP + col] = f2bf(acc[n][r]);
        }
    }
    if (XTnext) {
        ushort* Xn = XTnext + (size_t)(g * Bb + b) * XTR * NKP;
#pragma unroll
        for (int n = 0; n < 5; ++n) {
            int col = n * 16 + lr;
            ushort4 w;
#pragma unroll
            for (int r = 0; r < 4; ++r)
                w[r] = (col < INF) ? f2bf(acc[n][r]) : (ushort)0;
            *(ushort4*)(Xn + (size_t)col * NKP + rbase) = w;
        }
    }
}

// ================= gemm1: dsplit=16, 1 d per block, grid (16,50) = 800 blocks =================
// BM=64, BN=128. 4 waves 2x2 (wave = 32 rows x 64 cols). Double-buffered LDS +
// register prefetch, one barrier per K-step. LDS 30.7 KB.
__global__ __launch_bounds__(256, 4) void k_meta_d16(const ushort* __restrict__ Hbf,
        const ushort* __restrict__ WT, const float* __restrict__ emb,
        float* __restrict__ P) {
    constexpr int O = 128;
    __shared__ ushort As[2][64][40];
    __shared__ ushort Bs[2][O][40];
    const int d = blockIdx.x;       // 0..15
    const int bm = blockIdx.y * 64;
    const int t = threadIdx.x;
    const int wid = t >> 6, lane = t & 63;
    const int wm = wid >> 1, wn = wid & 1;
    const int lr = lane & 15, kq = lane >> 4;

    const int ar = t >> 2, akc = (t & 3) * 8;
    const ushort* srcA = Hbf + (size_t)(bm + ar) * KP + akc;
    int brow[2], bkc[2];
    const ushort* srcB[2];
#pragma unroll
    for (int p = 0; p < 2; ++p) {
        int chunk = t + p * 256;
        brow[p] = chunk >> 2; bkc[p] = (chunk & 3) * 8;
        srcB[p] = WT + ((size_t)d * O + brow[p]) * KP + bkc[p];
    }

    short8 ra, rb[2];
    ra = *(const short8*)srcA;
#pragma unroll
    for (int p = 0; p < 2; ++p) rb[p] = *(const short8*)srcB[p];

    f32x4 seg[2][4] = {};   // [m][n]

    for (int ks = 0; ks < 11; ++ks) {
        const int buf = ks & 1;
        *(short8*)&As[buf][ar][akc] = ra;
#pragma unroll
        for (int p = 0; p < 2; ++p) *(short8*)&Bs[buf][brow[p]][bkc[p]] = rb[p];
        if (ks < 10) {
            const int k0 = (ks + 1) * 32;
            ra = *(const short8*)(srcA + k0);
#pragma unroll
            for (int p = 0; p < 2; ++p) rb[p] = *(const short8*)(srcB[p] + k0);
        }
        __syncthreads();
        short8 a[2], bf[4];
#pragma unroll
        for (int m = 0; m < 2; ++m)
            a[m] = *(const short8*)&As[buf][wm * 32 + m * 16 + lr][kq * 8];
#pragma unroll
        for (int n = 0; n < 4; ++n)
            bf[n] = *(const short8*)&Bs[buf][wn * 64 + n * 16 + lr][kq * 8];
#pragma unroll
        for (int m = 0; m < 2; ++m)
#pragma unroll
            for (int n = 0; n < 4; ++n)
                seg[m][n] = __builtin_amdgcn_mfma_f32_16x16x32_bf16(a[m], bf[n], seg[m][n], 0, 0, 0);
    }

    float* Pd = P + (size_t)d * M * O;
#pragma unroll
    for (int m = 0; m < 2; ++m) {
        const int rbase = bm + wm * 32 + m * 16 + kq * 4;
#pragma unroll
        for (int r = 0; r < 4; ++r) {
            const int row = rbase + r;
            float e0 = emb[(size_t)row * EMB + d];
#pragma unroll
            for (int n = 0; n < 4; ++n) {
                const int col = wn * 64 + n * 16 + lr;
                Pd[(size_t)row * O + col] = e0 * seg[m][n][r];
            }
        }
    }
}

// ================= gemm2: dsplit=8 (2 d's share A), grid (8,50) — R5 verbatim =================
template <int O>
__global__ __launch_bounds__(256, 3) void k_meta_fused(const ushort* __restrict__ Hbf,
        const ushort* __restrict__ WT, const float* __restrict__ emb,
        float* __restrict__ P) {
    constexpr int NB = O / 32;
    constexpr int PB = O / 64;
    __shared__ ushort As[2][64][40];
    __shared__ ushort Bs[2][2][O][40];
    const int ds = blockIdx.x;
    const int bm = blockIdx.y * 64;
    const int t = threadIdx.x;
    const int wid = t >> 6, lane = t & 63;
    const int wm = wid >> 1, wn = wid & 1;
    const int lr = lane & 15, kq = lane >> 4;

    const int ar = t >> 2, akc = (t & 3) * 8;
    const ushort* srcA = Hbf + (size_t)(bm + ar) * KP + akc;
    const ushort* srcB[2][PB];
    int brow[PB], bkc[PB];
#pragma unroll
    for (int p = 0; p < PB; ++p) {
        int chunk = t + p * 256;
        brow[p] = chunk >> 2; bkc[p] = (chunk & 3) * 8;
#pragma unroll
        for (int j = 0; j < 2; ++j)
            srcB[j][p] = WT + ((size_t)(ds * 2 + j) * O + brow[p]) * KP + bkc[p];
    }

    short8 ra, rb[2][PB];
    ra = *(const short8*)srcA;
#pragma unroll
    for (int j = 0; j < 2; ++j)
#pragma unroll
        for (int p = 0; p < PB; ++p) rb[j][p] = *(const short8*)srcB[j][p];

    f32x4 seg[2][2][NB] = {};

    for (int ks = 0; ks < 11; ++ks) {
        const int buf = ks & 1;
        *(short8*)&As[buf][ar][akc] = ra;
#pragma unroll
        for (int j = 0; j < 2; ++j)
#pragma unroll
            for (int p = 0; p < PB; ++p) *(short8*)&Bs[buf][j][brow[p]][bkc[p]] = rb[j][p];
        if (ks < 10) {
            const int k0 = (ks + 1) * 32;
            ra = *(const short8*)(srcA + k0);
#pragma unroll
            for (int j = 0; j < 2; ++j)
#pragma unroll
                for (int p = 0; p < PB; ++p) rb[j][p] = *(const short8*)(srcB[j][p] + k0);
        }
        __syncthreads();
        short8 a[2], bf[2][NB];
#pragma unroll
        for (int m = 0; m < 2; ++m)
            a[m] = *(const short8*)&As[buf][wm * 32 + m * 16 + lr][kq * 8];
#pragma unroll
        for (int j = 0; j < 2; ++j)
#pragma unroll
            for (int n = 0; n < NB; ++n)
                bf[j][n] = *(const short8*)&Bs[buf][j][wn * (O / 2) + n * 16 + lr][kq * 8];
#pragma unroll
        for (int j = 0; j < 2; ++j)
#pragma unroll
            for (int m = 0; m < 2; ++m)
#pragma unroll
                for (int n = 0; n < NB; ++n)
                    seg[j][m][n] = __builtin_amdgcn_mfma_f32_16x16x32_bf16(a[m], bf[j][n], seg[j][m][n], 0, 0, 0);
    }

    float* Pd = P + (size_t)ds * M * O;
#pragma unroll
    for (int m = 0; m < 2; ++m) {
        const int rbase = bm + wm * 32 + m * 16 + kq * 4;
#pragma unroll
        for (int r = 0; r < 4; ++r) {
            const int row = rbase + r;
            float e0 = emb[(size_t)row * EMB + ds * 2];
            float e1 = emb[(size_t)row * EMB + ds * 2 + 1];
#pragma unroll
            for (int n = 0; n < NB; ++n) {
                const int col = wn * (O / 2) + n * 16 + lr;
                Pd[(size_t)row * O + col] = e0 * seg[0][m][n][r] + e1 * seg[1][m][n][r];
            }
        }
    }
}

// ================= z/r: sum 16 partials + bias + sigmoid; write z, r*state =================
__global__ void k_zr(const float* __restrict__ P, const float* __restrict__ emb,
                     const float* __restrict__ bg, const float* __restrict__ state,
                     float* __restrict__ zbuf, ushort* __restrict__ Hbf,
                     ushort* __restrict__ XTin) {
    __shared__ float es[2][EMB];
    const int t = threadIdx.x;
    if (t < 2 * EMB) es[t >> 4][t & 15] = emb[((size_t)blockIdx.x * 2 + (t >> 4)) * EMB + (t & 15)];
    __syncthreads();
    const int node = blockIdx.x * 2 + (t >> 7);
    const int o = t & 127;
    float v = 0.f;
#pragma unroll
    for (int s = 0; s < 16; ++s) v += P[((size_t)s * M + node) * 128 + o];
    const float* e_ = es[t >> 7];
#pragma unroll
    for (int d = 0; d < EMB; ++d) v += e_[d] * bg[d * 128 + o];
    float sg = 1.f / (1.f + expf(-v));
    if (o < 64) {
        zbuf[node * 64 + o] = sg;
    } else {
        int oo = o - 64;
        ushort bf = f2bf(sg * state[node * 64 + oo]);
        Hbf[(size_t)node * KP + 2 + oo] = bf;
        int b = node / Nn, kn = node % Nn;
        XTin[((size_t)b * XTR + 2 + oo) * NKP + kn] = bf;
    }
}

// ================= final: sum 8 partials + bias + tanh + GRU blend =================
__global__ void k_final(const float* __restrict__ P, const float* __restrict__ emb,
                        const float* __restrict__ bc, const float* __restrict__ zbuf,
                        const float* __restrict__ state, float* __restrict__ out) {
    __shared__ float es[4][EMB];
    const int t = threadIdx.x;
    if (t < 4 * EMB) es[t >> 4][t & 15] = emb[((size_t)blockIdx.x * 4 + (t >> 4)) * EMB + (t & 15)];
    __syncthreads();
    const int node = blockIdx.x * 4 + (t >> 6);
    const int o = t & 63;
    float v = 0.f;
#pragma unroll
    for (int s = 0; s < 8; ++s) v += P[((size_t)s * M + node) * 64 + o];
    const float* e_ = es[t >> 6];
#pragma unroll
    for (int d = 0; d < EMB; ++d) v += e_[d] * bc[d * 64 + o];
    float hc = tanhf(v);
    float z = zbuf[node * 64 + o];
    out[node * 64 + o] = z * state[node * 64 + o] + (1.f - z) * hc;
}

extern "C" void kernel_launch(void* const* d_in, const int* in_sizes, int n_in,
                              void* d_out, int out_size, void* d_ws, size_t ws_size,
                              hipStream_t stream) {
    const float* x      = (const float*)d_in[0];
    const float* state  = (const float*)d_in[1];
    const float* graphs = (const float*)d_in[2];
    const float* emb    = (const float*)d_in[3];
    const float* Wg     = (const float*)d_in[4];
    const float* bg     = (const float*)d_in[5];
    const float* Wc     = (const float*)d_in[6];
    const float* bc     = (const float*)d_in[7];
    float* out = (float*)d_out;

    char* ws = (char*)d_ws;
    ushort* Hbf  = (ushort*)ws;  ws += (size_t)M * KP * 2;                 // 2.25 MB
    ushort* Gbf  = (ushort*)ws;  ws += (size_t)GN * Bb * Nn * NKP * 2;     // 5.32 MB
    ushort* WgT  = (ushort*)ws;  ws += (size_t)2048 * KP * 2;              // 1.44 MB
    ushort* WcT  = (ushort*)ws;  ws += (size_t)1024 * KP * 2;              // 0.72 MB
    ushort* XTin = (ushort*)ws;  ws += (size_t)Bb * XTR * NKP * 2;         // 0.53 MB
    ushort* XTmid= (ushort*)ws;  ws += (size_t)GN * Bb * XTR * NKP * 2;    // 1.06 MB
    float*  PG   = (float*)ws;   ws += (size_t)16 * M * 128 * 4;           // 26.2 MB
    float*  PC   = (float*)ws;   ws += (size_t)8 * M * 64 * 4;             // 6.55 MB
    float*  zb   = (float*)ws;                                             // 0.82 MB

    dim3 hopgrid(25, Bb, GN);

    k_prep<<<3184, 256, 0, stream>>>(graphs, Wg, Wc, x, state, Gbf, WgT, WcT, Hbf, XTin);

    // ---- first meta_dgcn (gates) ----
    k_hop<<<hopgrid, 64, 0, stream>>>(Gbf, XTin, Hbf, XTmid, 66, 0);
    k_hop<<<hopgrid, 64, 0, stream>>>(Gbf, XTmid, Hbf, nullptr, 132, 1);
    k_meta_d16<<<dim3(16, 50), 256, 0, stream>>>(Hbf, WgT, emb, PG);
    k_zr<<<1600, 256, 0, stream>>>(PG, emb, bg, state, zb, Hbf, XTin);

    // ---- second meta_dgcn (candidate) ----
    k_hop<<<hopgrid, 64, 0, stream>>>(Gbf, XTin, Hbf, XTmid, 66, 0);
    k_hop<<<hopgrid, 64, 0, stream>>>(Gbf, XTmid, Hbf, nullptr, 132, 1);
    k_meta_fused<64><<<dim3(8, 50), 256, 0, stream>>>(Hbf, WcT, emb, PC);
    k_final<<<800, 256, 0, stream>>>(PC, emb, bc, zb, state, out);
}